// Round 1
// baseline (143.855 us; speedup 1.0000x reference)
//
#include <hip/hip_runtime.h>

// Problem constants (fixed by the reference): B=16 lists, N=1024, D=256.
#define BL 16
#define NL 1024
#define DD 256

typedef short bf16x8 __attribute__((ext_vector_type(8)));
typedef float f32x4 __attribute__((ext_vector_type(4)));

static __device__ __forceinline__ short f32_to_bf16(float f) {
  union { float f; unsigned u; } v; v.f = f;
  unsigned r = (v.u + 0x7FFFu + ((v.u >> 16) & 1u)) >> 16;  // RNE
  return (short)r;
}

// Async 16B global -> LDS. LDS dest must be wave-uniform base + lane*16
// (m104/m108). Global source address IS per-lane -> pre-swizzled source.
static __device__ __forceinline__ void g2l16(const short* g, short* l) {
  __builtin_amdgcn_global_load_lds(
      (const __attribute__((address_space(1))) void*)g,
      (__attribute__((address_space(3))) void*)l, 16, 0, 0);
}

// ---- Kernel 1: prep. Blocks [0,4096): X fp32->bf16. [4096,4608): W transpose.
__global__ __launch_bounds__(256) void k_prep(const float* __restrict__ X,
                                              const float* __restrict__ Wu,
                                              const float* __restrict__ Wl,
                                              short* __restrict__ Xb,
                                              short* __restrict__ WTu,
                                              short* __restrict__ WTl) {
  const int bid = blockIdx.x;
  if (bid < 4096) {
    int i = bid * 256 + threadIdx.x;  // float4 groups over 16384*256 floats
    const float4 v = ((const float4*)X)[i];
    short4 o;
    o.x = f32_to_bf16(v.x); o.y = f32_to_bf16(v.y);
    o.z = f32_to_bf16(v.z); o.w = f32_to_bf16(v.w);
    ((short4*)Xb)[i] = o;
  } else {
    const int id = bid - 4096;           // [0,512)
    const int z = id >> 8, d = id & 255; // matrix, source row of W
    const float* W = z ? Wl : Wu;
    short* WT = z ? WTl : WTu;
    const int e = threadIdx.x;
    WT[e * DD + d] = f32_to_bf16(W[d * DD + e]);  // WT[e][d] = W[d][e]
  }
}

// One stage-2 tile pass: C[64x64] = Y(p-strip, from LDS) * X(q-tile)^T, K=256.
// mode 0: store all; 1: store q>=p only (upper incl diag); 2: store q<p only.
// A-frags from XOR-swizzled LDS (byte ^= (row&7)<<4 -> 2-way conflict = free);
// B-frags direct global->VGPR (list X panel is L2-resident via XCD pinning).
static __device__ __forceinline__ void tile_pass(const short* __restrict__ Ylds,
                                                 const short* __restrict__ Bg,
                                                 float* __restrict__ Ob,
                                                 int p0, int q0, float bias,
                                                 int mode, int r, int quad) {
  f32x4 acc[4][4] = {};
#pragma unroll
  for (int ks = 0; ks < 8; ++ks) {
    bf16x8 af[4], bf[4];
#pragma unroll
    for (int mt = 0; mt < 4; ++mt) {
      const int row = mt * 16 + r;
      const int byte = (row * 512 + ks * 64 + quad * 16) ^ ((row & 7) << 4);
      af[mt] = *(const bf16x8*)((const char*)Ylds + byte);
    }
#pragma unroll
    for (int nt = 0; nt < 4; ++nt)
      bf[nt] = *(const bf16x8*)(Bg + (size_t)(nt * 16 + r) * DD + ks * 32 + quad * 8);
#pragma unroll
    for (int mt = 0; mt < 4; ++mt)
#pragma unroll
      for (int nt = 0; nt < 4; ++nt)
        acc[mt][nt] = __builtin_amdgcn_mfma_f32_16x16x32_bf16(af[mt], bf[nt],
                                                              acc[mt][nt], 0, 0, 0);
  }
#pragma unroll
  for (int mt = 0; mt < 4; ++mt)
#pragma unroll
    for (int nt = 0; nt < 4; ++nt) {
      const int q = q0 + nt * 16 + r;
#pragma unroll
      for (int i = 0; i < 4; ++i) {
        const int p = p0 + mt * 16 + quad * 4 + i;
        if (mode == 0 || (mode == 1 && q >= p) || (mode == 2 && q < p))
          Ob[(size_t)p * NL + q] = acc[mt][nt][i] + bias;
      }
    }
}

// ---- Kernel 2: fused stage1+stage2. One block per (list b, 64-row p-strip).
// Grid = 256 blocks (1/CU), bid = pt*16 + b so default XCD round-robin pins
// each list (X panel 512KB) to one XCD's L2. 512 threads = 8 waves.
// Phase 1: Y_U/Y_L[64x256] = Xp * W  (A staged to swizzled LDS, W streamed
//          from L2-hot WT; wave w owns output cols [w*32, w*32+32)).
// Phase 2 (barrier-free): wave w computes q-tiles qt=w and qt=w+8 of the
//          64x1024 output strip; diag tile done as two predicated passes.
__global__ __launch_bounds__(512) void k_fused(const short* __restrict__ Xb,
                                               const short* __restrict__ WTu,
                                               const short* __restrict__ WTl,
                                               const float* __restrict__ bu_p,
                                               const float* __restrict__ bl_p,
                                               float* __restrict__ out) {
  __shared__ short Asw[64 * 256];  // swizzled Xp strip, 32 KB
  __shared__ short Yu[64 * 256];   // swizzled Y_upper,  32 KB
  __shared__ short Yl[64 * 256];   // swizzled Y_lower,  32 KB

  const int bid = blockIdx.x;
  const int b = bid & 15, pt = bid >> 4;
  const int t = threadIdx.x, lane = t & 63, w = t >> 6;
  const int r = lane & 15, quad = lane >> 4;
  const size_t listoff = (size_t)b * NL * DD;
  const short* Ap = Xb + listoff + (size_t)pt * 64 * DD;  // 64 x 256 bf16

  // ---- stage Xp into LDS, XOR-swizzled via pre-swizzled global source ----
  // 16B chunk c lives at LDS byte c*16; its source is chunk (c&~31)|((c&31)^row&7)
  // so that reads at (row*512 + kbyte) ^ ((row&7)<<4) return A[row][kbyte..].
#pragma unroll
  for (int i = 0; i < 4; ++i) {
    const int c = i * 512 + t;  // per wave: uniform base + lane*16  (ok)
    const int src = (c & ~31) | ((c & 31) ^ ((c >> 5) & 7));
    g2l16(Ap + src * 8, Asw + c * 8);
  }
  __syncthreads();  // compiler drains vmcnt before s_barrier

  // ---- phase 1: Y = Xp * W for both matrices; wave w -> cols [w*32,+32) ----
  {
    const int n0 = w * 32;
    f32x4 aU[4][2] = {}, aL[4][2] = {};
#pragma unroll
    for (int ks = 0; ks < 8; ++ks) {
      bf16x8 af[4], bfu[2], bfl[2];
#pragma unroll
      for (int mt = 0; mt < 4; ++mt) {
        const int row = mt * 16 + r;
        const int byte = (row * 512 + ks * 64 + quad * 16) ^ ((row & 7) << 4);
        af[mt] = *(const bf16x8*)((const char*)Asw + byte);
      }
#pragma unroll
      for (int nt = 0; nt < 2; ++nt) {
        const int off = (n0 + nt * 16 + r) * DD + ks * 32 + quad * 8;
        bfu[nt] = *(const bf16x8*)(WTu + off);
        bfl[nt] = *(const bf16x8*)(WTl + off);
      }
#pragma unroll
      for (int mt = 0; mt < 4; ++mt)
#pragma unroll
        for (int nt = 0; nt < 2; ++nt) {
          aU[mt][nt] = __builtin_amdgcn_mfma_f32_16x16x32_bf16(af[mt], bfu[nt], aU[mt][nt], 0, 0, 0);
          aL[mt][nt] = __builtin_amdgcn_mfma_f32_16x16x32_bf16(af[mt], bfl[nt], aL[mt][nt], 0, 0, 0);
        }
    }
    // write Y (bf16) into swizzled LDS
#pragma unroll
    for (int mt = 0; mt < 4; ++mt)
#pragma unroll
      for (int nt = 0; nt < 2; ++nt)
#pragma unroll
        for (int i = 0; i < 4; ++i) {
          const int row = mt * 16 + quad * 4 + i;
          const int col = n0 + nt * 16 + r;
          const int byte = (row * 512 + col * 2) ^ ((row & 7) << 4);
          *(short*)((char*)Yu + byte) = f32_to_bf16(aU[mt][nt][i]);
          *(short*)((char*)Yl + byte) = f32_to_bf16(aL[mt][nt][i]);
        }
  }
  __syncthreads();

  // ---- phase 2: barrier-free; wave w owns q-tiles w and w+8 ----
  const float ubias = bu_p[0], lbias = bl_p[0];
  float* Ob = out + (size_t)b * NL * NL;
  const short* Bglist = Xb + listoff;
  const int p0 = pt * 64;

  for (int qq = 0; qq < 2; ++qq) {
    const int qt = w + qq * 8;
    const short* Bg = Bglist + (size_t)qt * 64 * DD;
    const int q0 = qt * 64;
    if (qt > pt) {
      tile_pass(Yu, Bg, Ob, p0, q0, ubias, 0, r, quad);
    } else if (qt < pt) {
      tile_pass(Yl, Bg, Ob, p0, q0, lbias, 0, r, quad);
    } else {
      tile_pass(Yu, Bg, Ob, p0, q0, ubias, 1, r, quad);  // q >= p
      tile_pass(Yl, Bg, Ob, p0, q0, lbias, 2, r, quad);  // q <  p
    }
  }
}

extern "C" void kernel_launch(void* const* d_in, const int* in_sizes, int n_in,
                              void* d_out, int out_size, void* d_ws, size_t ws_size,
                              hipStream_t stream) {
  const float* feats = (const float*)d_in[0];   // [B*N, D] fp32
  const float* Wu    = (const float*)d_in[1];   // [1, D, D]
  const float* bu    = (const float*)d_in[2];   // [1]
  const float* Wl    = (const float*)d_in[3];   // [1, D, D]
  const float* bl    = (const float*)d_in[4];   // [1]
  float* out = (float*)d_out;                   // [B, N, N] fp32

  char* ws = (char*)d_ws;
  short* Xb  = (short*)(ws);                                   // 8 MB bf16 X
  short* WTu = (short*)(ws + (size_t)8 * 1024 * 1024);         // 128 KB
  short* WTl = (short*)(ws + (size_t)8 * 1024 * 1024 + DD * DD * 2);

  // Prep: X->bf16 (4096 blocks) + W transpose (512 blocks), one dispatch.
  k_prep<<<4096 + 512, 256, 0, stream>>>(feats, Wu, Wl, Xb, WTu, WTl);

  // Fused stage1+stage2: 256 blocks (16 p-strips x 16 lists), 512 threads.
  // bid = pt*16 + b  ->  XCD = bid%8 = b%8: each list L2-pinned to one XCD.
  k_fused<<<256, 512, 0, stream>>>(Xb, WTu, WTl, bu, bl, out);
}